// Round 5
// baseline (78.714 us; speedup 1.0000x reference)
//
#include <hip/hip_runtime.h>
#include <math.h>

typedef __attribute__((ext_vector_type(8))) _Float16 f16x8;
typedef __attribute__((ext_vector_type(4))) float f32x4;

#define TSTEPS 23
#define ROWS 128
#define NPROD 34

// ws byte offsets
#define WSB_Z    0       // [64][64] f32 sigmoid LUT (16384 B)
#define WSB_B1   16384   // [64 n][168 k] f16 combined table *256 (21504 B)
#define WSB_W2   37888   // [64 n][72 k] f16 rw2 transposed (9216 B)
#define WSB_FLAG 49152   // u32 barrier flag

// LDS byte offsets (single 108800 B arena)
#define L_Z    0        // f32[64*64]        16384
#define L_B1   16384    // f16[64*168]       21504
#define L_W2   37888    // f16[64*72]         9216
#define L_H    47104    // f16[128*72]       18432
#define L_A    65536    // f16[128*168]      43008 (reused as f32[128][68] out)
#define L_RB2  108544   // f32[64]             256
// producer overlay lives in [47104, 108544):
#define P_EMB  47104    // f32[66*64]        16896
#define P_W    64000    // f32[128*64]       32768
#define P_V    96768    // f32[64*33]         8448
#define P_U    105216   // f32[4*32]           512
#define P_G    105728   // f32[65]             260
#define P_RB1  106240   // f32[64]             256

__global__ __launch_bounds__(512, 2) void sm_fused(
    const int* __restrict__ seqs, const int* __restrict__ qtok,
    const float* __restrict__ embed, const float* __restrict__ gw1,
    const float* __restrict__ gb1, const float* __restrict__ gw2,
    const float* __restrict__ gb2, const float* __restrict__ rw1,
    const float* __restrict__ rb1, const float* __restrict__ rw2,
    const float* __restrict__ rb2,
    char* __restrict__ wsc, float* __restrict__ out)
{
    __shared__ __align__(16) char smem[108800];
    float*    sZ   = (float*)(smem + L_Z);
    _Float16* sB1  = (_Float16*)(smem + L_B1);
    _Float16* sW2  = (_Float16*)(smem + L_W2);
    _Float16* sH   = (_Float16*)(smem + L_H);
    _Float16* sA   = (_Float16*)(smem + L_A);
    float*    sRb2 = (float*)(smem + L_RB2);

    const int tid = threadIdx.x;
    const int blk = blockIdx.x;
    const int base = blk * ROWS;
    unsigned* flag = (unsigned*)(wsc + WSB_FLAG);

    // ---- early prefetch (hides HBM latency under producer work / spin) ----
    unsigned pk[6];
    int qt = 0;
    if (tid < ROWS) {
        const int4* sq = (const int4*)(seqs + (size_t)(base + tid) * 24);
        #pragma unroll
        for (int i = 0; i < 6; ++i) {
            const int4 w4 = sq[i];
            pk[i] = (unsigned)w4.x | ((unsigned)w4.y << 8) |
                    ((unsigned)w4.z << 16) | ((unsigned)w4.w << 24);
        }
        qt = qtok[base + tid];
    }
    float rb2v = 0.f;
    if (tid < 64) rb2v = rb2[tid];

    // ---- producer phase: blocks 0..33 build tables (bitwise == R4 pre_all) ----
    if (blk < NPROD) {
        float* pEmb = (float*)(smem + P_EMB);
        float* pW   = (float*)(smem + P_W);
        if (blk < 16) {
            float* pV = (float*)(smem + P_V);
            float* pU = (float*)(smem + P_U);
            float* pG = (float*)(smem + P_G);
            {
                const float4* es = (const float4*)embed;
                float4* ed = (float4*)pEmb;
                for (int i = tid; i < 1024; i += 512) ed[i] = es[i];
                const float4* gs = (const float4*)gw1;
                float4* gd = (float4*)pW;
                for (int i = tid; i < 1024; i += 512) gd[i] = gs[i];
                if (tid < 32) { pG[tid] = gb1[tid]; pG[32 + tid] = gw2[tid]; }
                if (tid == 64) pG[64] = gb2[0];
            }
            __syncthreads();
            #pragma unroll
            for (int i = 0; i < 4; ++i) {                 // v: 64 s × 32 j
                const int e = tid + i * 512;
                const int s = e >> 5, j = e & 31;
                float acc = 0.f;
                const float* er = pEmb + s * 64;
                #pragma unroll
                for (int k = 0; k < 64; ++k)
                    acc = fmaf(er[k], pW[(64 + k) * 32 + j], acc);
                pV[s * 33 + j] = acc;
            }
            if (tid < 128) {                              // u: 4 c-rows × 32 j
                const int cc = tid >> 5, j = tid & 31;
                const int c = blk * 4 + cc;
                float acc = 0.f;
                const float* er = pEmb + c * 64;
                #pragma unroll
                for (int k = 0; k < 64; ++k)
                    acc = fmaf(er[k], pW[k * 32 + j], acc);
                pU[cc * 32 + j] = acc;
            }
            __syncthreads();
            if (tid < 256) {                              // DP finisher
                const int cc = tid >> 6, s = tid & 63;
                const int c = blk * 4 + cc;
                double z = (double)pG[64];
                #pragma unroll
                for (int j = 0; j < 32; ++j) {
                    const double a = (double)pU[cc * 32 + j] + (double)pV[s * 33 + j] + (double)pG[j];
                    if (a > 0.0) z += a * (double)pG[32 + j];
                }
                ((float*)(wsc + WSB_Z))[c * 64 + s] = (float)(1.0 / (1.0 + exp(-z)));
            }
        } else if (blk < 33) {
            float* pRb1 = (float*)(smem + P_RB1);
            {
                const float4* es = (const float4*)embed;
                float4* ed = (float4*)pEmb;
                for (int i = tid; i < 1056; i += 512) ed[i] = es[i];
                const float4* rs = (const float4*)rw1;
                float4* rd = (float4*)pW;
                for (int i = tid; i < 2048; i += 512) rd[i] = rs[i];
                if (tid < 64) pRb1[tid] = rb1[tid];
            }
            __syncthreads();
            const int e = (blk - 16) * 512 + tid;
            if (e < 8320) {
                const int n = e & 63, k = e >> 6;         // k < 130
                float acc;
                if (k < 64) {                             // counts side (mem half)
                    acc = 0.f;
                    const float* er = pEmb + k * 64;
                    #pragma unroll
                    for (int m = 0; m < 64; ++m)
                        acc = fmaf(er[m], pW[(64 + m) * 64 + n], acc);
                    acc *= 0.125f * 256.f;
                } else {                                  // query side (ctx half + rb1)
                    const int t = k - 64;
                    acc = pRb1[n];
                    const float* er = pEmb + t * 64;
                    #pragma unroll
                    for (int m = 0; m < 64; ++m)
                        acc = fmaf(er[m], pW[m * 64 + n], acc);
                    acc *= 256.f;
                }
                ((_Float16*)(wsc + WSB_B1))[n * 168 + k] = (_Float16)acc;
            }
        } else {
            _Float16* w2t = (_Float16*)(wsc + WSB_W2);
            for (int e = tid; e < 4096; e += 512) {
                const int n = e & 63, j = e >> 6;
                w2t[n * 72 + j] = (_Float16)rw2[j * 64 + n];
            }
            _Float16* b1 = (_Float16*)(wsc + WSB_B1);
            for (int e = tid; e < 2432; e += 512) {       // k in [130,168)
                const int n = e / 38, k = 130 + (e - n * 38);
                b1[n * 168 + k] = (_Float16)0.f;
            }
        }
        __syncthreads();          // all stores issued+drained (vmcnt(0) at barrier)
        __threadfence();          // agent-scope release: write back L2
        if (tid == 0)
            __hip_atomic_fetch_add(flag, 1u, __ATOMIC_RELEASE, __HIP_MEMORY_SCOPE_AGENT);
    }

    // ---- manual grid barrier: wait for all 34 producers ----
    if (tid == 0) {
        while (__hip_atomic_load(flag, __ATOMIC_ACQUIRE, __HIP_MEMORY_SCOPE_AGENT) < (unsigned)NPROD)
            __builtin_amdgcn_s_sleep(8);
    }
    __syncthreads();

    // ---- phase 0: stage Z (coherent u64 loads) + zero A + rb2 ----
    {
        const unsigned long long* zsrc = (const unsigned long long*)(wsc + WSB_Z);
        unsigned long long* zdst = (unsigned long long*)sZ;
        #pragma unroll
        for (int i = 0; i < 4; ++i)
            zdst[tid + i * 512] =
                __hip_atomic_load(&zsrc[tid + i * 512], __ATOMIC_RELAXED, __HIP_MEMORY_SCOPE_AGENT);
        const float4 z4 = {0.f, 0.f, 0.f, 0.f};
        float4* ad = (float4*)sA;
        for (int i = tid; i < 2688; i += 512) ad[i] = z4;
        if (tid < 64) sRb2[tid] = rb2v;
    }
    __syncthreads();

    // ---- phase 1: scan + A build (tid<128) || stage B1/W2 (tid>=128) ----
    if (tid < ROWS) {
        unsigned lo = pk[0], hi = pk[1];
        #pragma unroll
        for (int t = 8; t < TSTEPS; ++t) {
            const int c = (int)((pk[t >> 2] >> ((t & 3) * 8)) & 255u);
            const float* zr = sZ + c * 64;
            float b = zr[lo & 63]; int am = 0; float z;
            z = zr[(lo >> 8) & 63];  if (z > b) { b = z; am = 1; }
            z = zr[(lo >> 16) & 63]; if (z > b) { b = z; am = 2; }
            z = zr[lo >> 24];        if (z > b) { b = z; am = 3; }
            z = zr[hi & 63];         if (z > b) { b = z; am = 4; }
            z = zr[(hi >> 8) & 63];  if (z > b) { b = z; am = 5; }
            z = zr[(hi >> 16) & 63]; if (z > b) { b = z; am = 6; }
            z = zr[hi >> 24];        if (z > b) { b = z; am = 7; }
            const unsigned cb = (unsigned)c;
            if (am < 4) { const int sh = am * 8; lo = (lo & ~(255u << sh)) | (cb << sh); }
            else        { const int sh = am * 8 - 32; hi = (hi & ~(255u << sh)) | (cb << sh); }
        }
        int t_[8] = { (int)(lo & 63), (int)((lo >> 8) & 63), (int)((lo >> 16) & 63), (int)(lo >> 24),
                      (int)(hi & 63), (int)((hi >> 8) & 63), (int)((hi >> 16) & 63), (int)(hi >> 24) };
        int tot[8] = {1, 1, 1, 1, 1, 1, 1, 1};
        #pragma unroll
        for (int i = 0; i < 8; ++i)
            #pragma unroll
            for (int j = i + 1; j < 8; ++j) {
                const int eq = (t_[i] == t_[j]);
                tot[i] += eq; tot[j] += eq;
            }
        _Float16* arow = sA + tid * 168;
        #pragma unroll
        for (int i = 0; i < 8; ++i) arow[t_[i]] = (_Float16)(float)tot[i];
        arow[64 + qt] = (_Float16)1.0f;
    } else {
        const int t2 = tid - 128;   // 0..383
        const unsigned long long* b1s = (const unsigned long long*)(wsc + WSB_B1);
        unsigned long long* b1d = (unsigned long long*)sB1;
        for (int i = t2; i < 2688; i += 384)
            b1d[i] = __hip_atomic_load(&b1s[i], __ATOMIC_RELAXED, __HIP_MEMORY_SCOPE_AGENT);
        const unsigned long long* w2s = (const unsigned long long*)(wsc + WSB_W2);
        unsigned long long* w2d = (unsigned long long*)sW2;
        for (int i = t2; i < 1152; i += 384)
            w2d[i] = __hip_atomic_load(&w2s[i], __ATOMIC_RELAXED, __HIP_MEMORY_SCOPE_AGENT);
    }
    __syncthreads();

    // ---- MFMA-1: h = A @ B1 (K=160), relu -> sH fp16 ----
    const int lane = tid & 63;
    const int w = tid >> 6;                 // 0..7
    const int c16 = lane & 15, g = lane >> 4;
    const int arow = w * 16 + c16;          // 0..127
    f32x4 a0 = {0.f, 0.f, 0.f, 0.f}, a1 = a0, a2 = a0, a3 = a0;
    #pragma unroll
    for (int ks = 0; ks < 5; ++ks) {
        const int ko = ks * 32 + g * 8;
        const f16x8 af = *(const f16x8*)&sA[arow * 168 + ko];
        const f16x8 b0 = *(const f16x8*)&sB1[(c16) * 168 + ko];
        const f16x8 b1 = *(const f16x8*)&sB1[(16 + c16) * 168 + ko];
        const f16x8 b2 = *(const f16x8*)&sB1[(32 + c16) * 168 + ko];
        const f16x8 b3 = *(const f16x8*)&sB1[(48 + c16) * 168 + ko];
        a0 = __builtin_amdgcn_mfma_f32_16x16x32_f16(af, b0, a0, 0, 0, 0);
        a1 = __builtin_amdgcn_mfma_f32_16x16x32_f16(af, b1, a1, 0, 0, 0);
        a2 = __builtin_amdgcn_mfma_f32_16x16x32_f16(af, b2, a2, 0, 0, 0);
        a3 = __builtin_amdgcn_mfma_f32_16x16x32_f16(af, b3, a3, 0, 0, 0);
    }
    {
        const int rbase = w * 16 + g * 4;
        #pragma unroll
        for (int j = 0; j < 4; ++j) {
            _Float16* hr = sH + (rbase + j) * 72;
            const float v0 = a0[j], v1 = a1[j], v2 = a2[j], v3 = a3[j];
            hr[c16]      = (_Float16)(v0 > 0.f ? v0 : 0.f);
            hr[16 + c16] = (_Float16)(v1 > 0.f ? v1 : 0.f);
            hr[32 + c16] = (_Float16)(v2 > 0.f ? v2 : 0.f);
            hr[48 + c16] = (_Float16)(v3 > 0.f ? v3 : 0.f);
        }
    }
    __syncthreads();

    // ---- MFMA-2: logits = relu(h) @ W2t (K=64) ----
    f32x4 d0 = {0.f, 0.f, 0.f, 0.f}, d1 = d0, d2 = d0, d3 = d0;
    #pragma unroll
    for (int ks = 0; ks < 2; ++ks) {
        const int ko = ks * 32 + g * 8;
        const f16x8 af = *(const f16x8*)&sH[arow * 72 + ko];
        const f16x8 b0 = *(const f16x8*)&sW2[(c16) * 72 + ko];
        const f16x8 b1 = *(const f16x8*)&sW2[(16 + c16) * 72 + ko];
        const f16x8 b2 = *(const f16x8*)&sW2[(32 + c16) * 72 + ko];
        const f16x8 b3 = *(const f16x8*)&sW2[(48 + c16) * 72 + ko];
        d0 = __builtin_amdgcn_mfma_f32_16x16x32_f16(af, b0, d0, 0, 0, 0);
        d1 = __builtin_amdgcn_mfma_f32_16x16x32_f16(af, b1, d1, 0, 0, 0);
        d2 = __builtin_amdgcn_mfma_f32_16x16x32_f16(af, b2, d2, 0, 0, 0);
        d3 = __builtin_amdgcn_mfma_f32_16x16x32_f16(af, b3, d3, 0, 0, 0);
    }
    float* sOut = (float*)(void*)sA;        // reuse sA: [128][68] f32
    {
        const int rbase = w * 16 + g * 4;
        #pragma unroll
        for (int j = 0; j < 4; ++j) {
            float* orow = sOut + (rbase + j) * 68;
            orow[c16]      = d0[j] * (1.f / 256.f) + sRb2[c16];
            orow[16 + c16] = d1[j] * (1.f / 256.f) + sRb2[16 + c16];
            orow[32 + c16] = d2[j] * (1.f / 256.f) + sRb2[32 + c16];
            orow[48 + c16] = d3[j] * (1.f / 256.f) + sRb2[48 + c16];
        }
    }
    __syncthreads();

    // ---- coalesced store: 128 rows × 64 f32 ----
    #pragma unroll
    for (int r2 = 0; r2 < 4; ++r2) {
        const int idx = r2 * 512 + tid;
        const int row = idx >> 4, c4 = idx & 15;
        *(float4*)(out + (size_t)(base + row) * 64 + c4 * 4) =
            *(const float4*)&sOut[row * 68 + c4 * 4];
    }
}

extern "C" void kernel_launch(void* const* d_in, const int* in_sizes, int n_in,
                              void* d_out, int out_size, void* d_ws, size_t ws_size,
                              hipStream_t stream)
{
    const int* seqs    = (const int*)d_in[0];
    const int* qtok    = (const int*)d_in[1];
    const float* embed = (const float*)d_in[2];
    const float* gw1   = (const float*)d_in[3];
    const float* gb1   = (const float*)d_in[4];
    const float* gw2   = (const float*)d_in[5];
    const float* gb2   = (const float*)d_in[6];
    const float* rw1   = (const float*)d_in[7];
    const float* rb1   = (const float*)d_in[8];
    const float* rw2   = (const float*)d_in[9];
    const float* rb2   = (const float*)d_in[10];
    char* wsc  = (char*)d_ws;
    float* out = (float*)d_out;
    const int B = in_sizes[1];

    hipMemsetAsync(wsc + WSB_FLAG, 0, 4, stream);
    sm_fused<<<B / ROWS, 512, 0, stream>>>(seqs, qtok, embed, gw1, gb1, gw2, gb2,
                                           rw1, rb1, rw2, rb2, wsc, out);
}

// Round 6
// 43.382 us; speedup vs baseline: 1.8144x; 1.8144x over previous
//
#include <hip/hip_runtime.h>
#include <math.h>

typedef __attribute__((ext_vector_type(8))) _Float16 f16x8;
typedef __attribute__((ext_vector_type(4))) float f32x4;

#define TSTEPS 23
#define ROWS 128

// ws byte offsets
#define WSB_B1 0        // [64 n][168 k] f16 combined table *256 (21504 B)
#define WSB_W2 21504    // [64 n][72 k] f16 rw2 transposed (9216 B)
#define WSB_U  30720    // [64 c][32 j] f32 ctx gate proj (8192 B)
#define WSB_V  38912    // [64 s][32 j] f32 mem gate proj (8192 B)

// ---- stage 1: light blocks only (verbatim R3 pre_tables numerics) ----
__global__ __launch_bounds__(256) void pre_lite(
    const float* __restrict__ embed, const float* __restrict__ gw1,
    const float* __restrict__ rw1, const float* __restrict__ rb1,
    const float* __restrict__ rw2, char* __restrict__ wsc)
{
    __shared__ float sEmb[66 * 64];
    __shared__ float sW[128 * 64];
    __shared__ float sRb1[64];

    const int tid = threadIdx.x;
    const int blk = blockIdx.x;

    if (blk < 16) {
        // ---- u/v gate projections: 4096 outputs, 1/thread ----
        {
            const float4* es = (const float4*)embed;
            float4* ed = (float4*)sEmb;
            for (int i = tid; i < 1056; i += 256) ed[i] = es[i];
            const float4* gs = (const float4*)gw1;       // [128][32]
            float4* gd = (float4*)sW;
            for (int i = tid; i < 1024; i += 256) gd[i] = gs[i];
        }
        __syncthreads();
        const int e = blk * 256 + tid;                   // 0..4095
        const int row = (e >> 5) & 63, j = e & 31;
        const int ofs = (e < 2048) ? 0 : 64;
        float acc = 0.f;
        const float* er = sEmb + row * 64;
        #pragma unroll
        for (int k = 0; k < 64; ++k)
            acc = fmaf(er[k], sW[(ofs + k) * 32 + j], acc);
        float* dst = (float*)(wsc + ((e < 2048) ? WSB_U : WSB_V));
        dst[e & 2047] = acc;
    } else if (blk < 49) {
        // ---- B1 combined table: 8320 outputs, 1/thread ----
        {
            const float4* es = (const float4*)embed;
            float4* ed = (float4*)sEmb;
            for (int i = tid; i < 1056; i += 256) ed[i] = es[i];
            const float4* rs = (const float4*)rw1;       // [128][64]
            float4* rd = (float4*)sW;
            for (int i = tid; i < 2048; i += 256) rd[i] = rs[i];
            if (tid < 64) sRb1[tid] = rb1[tid];
        }
        __syncthreads();
        const int e = (blk - 16) * 256 + tid;
        if (e < 8320) {
            const int n = e & 63, k = e >> 6;            // k < 130
            float acc;
            if (k < 64) {                                // counts side (mem half)
                acc = 0.f;
                const float* er = sEmb + k * 64;
                #pragma unroll
                for (int m = 0; m < 64; ++m)
                    acc = fmaf(er[m], sW[(64 + m) * 64 + n], acc);
                acc *= 0.125f * 256.f;
            } else {                                     // query side (ctx half + rb1)
                const int t = k - 64;
                acc = sRb1[n];
                const float* er = sEmb + t * 64;
                #pragma unroll
                for (int m = 0; m < 64; ++m)
                    acc = fmaf(er[m], sW[m * 64 + n], acc);
                acc *= 256.f;
            }
            ((_Float16*)(wsc + WSB_B1))[n * 168 + k] = (_Float16)acc;
        }
    } else {
        // ---- W2 transpose + B1 k-pads ----
        _Float16* w2t = (_Float16*)(wsc + WSB_W2);
        for (int e = tid; e < 4096; e += 256) {
            const int n = e & 63, j = e >> 6;
            w2t[n * 72 + j] = (_Float16)rw2[j * 64 + n];
        }
        _Float16* b1 = (_Float16*)(wsc + WSB_B1);
        for (int e = tid; e < 2432; e += 256) {          // k in [130,168)
            const int n = e / 38, k = 130 + (e - n * 38);
            b1[n * 168 + k] = (_Float16)0.f;
        }
    }
}

// LDS byte offsets (109056 B arena)
#define L_A    0        // f16[128][168] 43008 (reused as f32[128][68] out)
#define L_B1   43008    // f16[64][168]  21504
#define L_W2   64512    // f16[64][72]    9216
#define L_Z    73728    // f32[64][65]   16640
#define L_H    90368    // f16[128][72]  18432 — overlaid pre-scan by sU/sV
#define L_U    90368    // f32[64][33]    8448
#define L_V    98816    // f32[64][33]    8448
#define L_G    107264   // f32[65]: gb1[0:32], gw2[32:64], gb2[64]
#define L_RB2  108800   // f32[64]

__global__ __launch_bounds__(512, 2) void sm_main(
    const int* __restrict__ seqs, const int* __restrict__ qtok,
    const float* __restrict__ gb1, const float* __restrict__ gw2,
    const float* __restrict__ gb2, const float* __restrict__ rb2,
    const char* __restrict__ wsc, float* __restrict__ out)
{
    __shared__ __align__(16) char smem[109056];
    _Float16* sA   = (_Float16*)(smem + L_A);
    _Float16* sB1  = (_Float16*)(smem + L_B1);
    _Float16* sW2  = (_Float16*)(smem + L_W2);
    float*    sZ   = (float*)(smem + L_Z);
    _Float16* sH   = (_Float16*)(smem + L_H);
    float*    sU   = (float*)(smem + L_U);
    float*    sV   = (float*)(smem + L_V);
    float*    sG   = (float*)(smem + L_G);
    float*    sRb2 = (float*)(smem + L_RB2);

    const int tid = threadIdx.x;
    const int base = blockIdx.x * ROWS;

    // ---- early prefetch: tokens (latency hides under staging/Z-compute) ----
    unsigned pk[6];
    int qt = 0;
    if (tid < ROWS) {
        const int4* sq = (const int4*)(seqs + (size_t)(base + tid) * 24);
        #pragma unroll
        for (int i = 0; i < 6; ++i) {
            const int4 w4 = sq[i];
            pk[i] = (unsigned)w4.x | ((unsigned)w4.y << 8) |
                    ((unsigned)w4.z << 16) | ((unsigned)w4.w << 24);
        }
        qt = qtok[base + tid];
    }

    // ---- phase 0: stage u/v (padded) + gate consts + rb2 + zero A ----
    {
        const float* u = (const float*)(wsc + WSB_U);
        const float* v = (const float*)(wsc + WSB_V);
        #pragma unroll
        for (int i = 0; i < 4; ++i) {
            const int e = tid + i * 512;
            sU[(e >> 5) * 33 + (e & 31)] = u[e];
            sV[(e >> 5) * 33 + (e & 31)] = v[e];
        }
        if (tid < 32) { sG[tid] = gb1[tid]; sG[32 + tid] = gw2[tid]; }
        if (tid == 64) sG[64] = gb2[0];
        if (tid < 64) sRb2[tid] = rb2[tid];
        const float4 z4 = {0.f, 0.f, 0.f, 0.f};
        float4* ad = (float4*)sA;
        for (int i = tid; i < 2688; i += 512) ad[i] = z4;
    }
    __syncthreads();

    // ---- phase 1: issue B1/W2 loads early; Z f64 finisher hides latency ----
    float4 stg[4];
    {
        const float4* b1s = (const float4*)(wsc + WSB_B1);  // 1344 f4
        const float4* w2s = (const float4*)(wsc + WSB_W2);  // 576 f4
        #pragma unroll
        for (int m = 0; m < 4; ++m) {
            const int flat = tid + m * 512;
            if (flat < 1344)      stg[m] = b1s[flat];
            else if (flat < 1920) stg[m] = w2s[flat - 1344];
        }
    }
    #pragma unroll
    for (int i = 0; i < 8; ++i) {                        // Z: 4096 entries, 8/thread
        const int idx = tid + i * 512;
        const int c = idx >> 6, s = idx & 63;
        double z = (double)sG[64];
        #pragma unroll
        for (int j = 0; j < 32; ++j) {
            const double a = (double)sU[c * 33 + j] + (double)sV[s * 33 + j] + (double)sG[j];
            if (a > 0.0) z += a * (double)sG[32 + j];
        }
        sZ[c * 65 + s] = (float)(1.0 / (1.0 + exp(-z)));
    }
    __syncthreads();   // sU/sV dead from here; sH region free for reuse

    // ---- phase 1b: land B1/W2 into LDS ----
    {
        float4* b1d = (float4*)sB1;
        float4* w2d = (float4*)sW2;
        #pragma unroll
        for (int m = 0; m < 4; ++m) {
            const int flat = tid + m * 512;
            if (flat < 1344)      b1d[flat] = stg[m];
            else if (flat < 1920) w2d[flat - 1344] = stg[m];
        }
    }
    __syncthreads();

    // ---- phase 2: scan + A build (tid<128, waves 0-1) ----
    if (tid < ROWS) {
        unsigned lo = pk[0], hi = pk[1];
        #pragma unroll
        for (int t = 8; t < TSTEPS; ++t) {
            const int c = (int)((pk[t >> 2] >> ((t & 3) * 8)) & 255u);
            const float* zr = sZ + c * 65;
            float b = zr[lo & 63]; int am = 0; float z;
            z = zr[(lo >> 8) & 63];  if (z > b) { b = z; am = 1; }
            z = zr[(lo >> 16) & 63]; if (z > b) { b = z; am = 2; }
            z = zr[lo >> 24];        if (z > b) { b = z; am = 3; }
            z = zr[hi & 63];         if (z > b) { b = z; am = 4; }
            z = zr[(hi >> 8) & 63];  if (z > b) { b = z; am = 5; }
            z = zr[(hi >> 16) & 63]; if (z > b) { b = z; am = 6; }
            z = zr[hi >> 24];        if (z > b) { b = z; am = 7; }
            const unsigned cb = (unsigned)c;
            if (am < 4) { const int sh = am * 8; lo = (lo & ~(255u << sh)) | (cb << sh); }
            else        { const int sh = am * 8 - 32; hi = (hi & ~(255u << sh)) | (cb << sh); }
        }
        int t_[8] = { (int)(lo & 63), (int)((lo >> 8) & 63), (int)((lo >> 16) & 63), (int)(lo >> 24),
                      (int)(hi & 63), (int)((hi >> 8) & 63), (int)((hi >> 16) & 63), (int)(hi >> 24) };
        int tot[8] = {1, 1, 1, 1, 1, 1, 1, 1};
        #pragma unroll
        for (int i = 0; i < 8; ++i)
            #pragma unroll
            for (int j = i + 1; j < 8; ++j) {
                const int eq = (t_[i] == t_[j]);
                tot[i] += eq; tot[j] += eq;
            }
        _Float16* arow = sA + tid * 168;
        #pragma unroll
        for (int i = 0; i < 8; ++i) arow[t_[i]] = (_Float16)(float)tot[i];
        arow[64 + qt] = (_Float16)1.0f;
    }
    __syncthreads();

    // ---- MFMA-1: h = A @ B1 (K=160), relu -> sH fp16 ----
    const int lane = tid & 63;
    const int w = tid >> 6;                 // 0..7
    const int c16 = lane & 15, g = lane >> 4;
    const int arow = w * 16 + c16;          // 0..127
    f32x4 a0 = {0.f, 0.f, 0.f, 0.f}, a1 = a0, a2 = a0, a3 = a0;
    #pragma unroll
    for (int ks = 0; ks < 5; ++ks) {
        const int ko = ks * 32 + g * 8;
        const f16x8 af = *(const f16x8*)&sA[arow * 168 + ko];
        const f16x8 b0 = *(const f16x8*)&sB1[(c16) * 168 + ko];
        const f16x8 b1 = *(const f16x8*)&sB1[(16 + c16) * 168 + ko];
        const f16x8 b2 = *(const f16x8*)&sB1[(32 + c16) * 168 + ko];
        const f16x8 b3 = *(const f16x8*)&sB1[(48 + c16) * 168 + ko];
        a0 = __builtin_amdgcn_mfma_f32_16x16x32_f16(af, b0, a0, 0, 0, 0);
        a1 = __builtin_amdgcn_mfma_f32_16x16x32_f16(af, b1, a1, 0, 0, 0);
        a2 = __builtin_amdgcn_mfma_f32_16x16x32_f16(af, b2, a2, 0, 0, 0);
        a3 = __builtin_amdgcn_mfma_f32_16x16x32_f16(af, b3, a3, 0, 0, 0);
    }
    {
        const int rbase = w * 16 + g * 4;
        #pragma unroll
        for (int j = 0; j < 4; ++j) {
            _Float16* hr = sH + (rbase + j) * 72;
            const float v0 = a0[j], v1 = a1[j], v2 = a2[j], v3 = a3[j];
            hr[c16]      = (_Float16)(v0 > 0.f ? v0 : 0.f);
            hr[16 + c16] = (_Float16)(v1 > 0.f ? v1 : 0.f);
            hr[32 + c16] = (_Float16)(v2 > 0.f ? v2 : 0.f);
            hr[48 + c16] = (_Float16)(v3 > 0.f ? v3 : 0.f);
        }
    }
    __syncthreads();

    // ---- MFMA-2: logits = relu(h) @ W2t (K=64) ----
    f32x4 d0 = {0.f, 0.f, 0.f, 0.f}, d1 = d0, d2 = d0, d3 = d0;
    #pragma unroll
    for (int ks = 0; ks < 2; ++ks) {
        const int ko = ks * 32 + g * 8;
        const f16x8 af = *(const f16x8*)&sH[arow * 72 + ko];
        const f16x8 b0 = *(const f16x8*)&sW2[(c16) * 72 + ko];
        const f16x8 b1 = *(const f16x8*)&sW2[(16 + c16) * 72 + ko];
        const f16x8 b2 = *(const f16x8*)&sW2[(32 + c16) * 72 + ko];
        const f16x8 b3 = *(const f16x8*)&sW2[(48 + c16) * 72 + ko];
        d0 = __builtin_amdgcn_mfma_f32_16x16x32_f16(af, b0, d0, 0, 0, 0);
        d1 = __builtin_amdgcn_mfma_f32_16x16x32_f16(af, b1, d1, 0, 0, 0);
        d2 = __builtin_amdgcn_mfma_f32_16x16x32_f16(af, b2, d2, 0, 0, 0);
        d3 = __builtin_amdgcn_mfma_f32_16x16x32_f16(af, b3, d3, 0, 0, 0);
    }
    float* sOut = (float*)(void*)sA;        // reuse sA: [128][68] f32
    {
        const int rbase = w * 16 + g * 4;
        #pragma unroll
        for (int j = 0; j < 4; ++j) {
            float* orow = sOut + (rbase + j) * 68;
            orow[c16]      = d0[j] * (1.f / 256.f) + sRb2[c16];
            orow[16 + c16] = d1[j] * (1.f / 256.f) + sRb2[16 + c16];
            orow[32 + c16] = d2[j] * (1.f / 256.f) + sRb2[32 + c16];
            orow[48 + c16] = d3[j] * (1.f / 256.f) + sRb2[48 + c16];
        }
    }
    __syncthreads();

    // ---- coalesced store: 128 rows × 64 f32 ----
    #pragma unroll
    for (int r2 = 0; r2 < 4; ++r2) {
        const int idx = r2 * 512 + tid;
        const int row = idx >> 4, c4 = idx & 15;
        *(float4*)(out + (size_t)(base + row) * 64 + c4 * 4) =
            *(const float4*)&sOut[row * 68 + c4 * 4];
    }
}

extern "C" void kernel_launch(void* const* d_in, const int* in_sizes, int n_in,
                              void* d_out, int out_size, void* d_ws, size_t ws_size,
                              hipStream_t stream)
{
    const int* seqs    = (const int*)d_in[0];
    const int* qtok    = (const int*)d_in[1];
    const float* embed = (const float*)d_in[2];
    const float* gw1   = (const float*)d_in[3];
    const float* gb1   = (const float*)d_in[4];
    const float* gw2   = (const float*)d_in[5];
    const float* gb2   = (const float*)d_in[6];
    const float* rw1   = (const float*)d_in[7];
    const float* rb1   = (const float*)d_in[8];
    const float* rw2   = (const float*)d_in[9];
    const float* rb2   = (const float*)d_in[10];
    char* wsc  = (char*)d_ws;
    float* out = (float*)d_out;
    const int B = in_sizes[1];

    pre_lite<<<50, 256, 0, stream>>>(embed, gw1, rw1, rb1, rw2, wsc);
    sm_main<<<B / ROWS, 512, 0, stream>>>(seqs, qtok, gb1, gw2, gb2, rb2, wsc, out);
}

// Round 7
// 23.716 us; speedup vs baseline: 3.3191x; 1.8293x over previous
//
#include <hip/hip_runtime.h>
#include <math.h>

typedef __attribute__((ext_vector_type(8))) _Float16 f16x8;
typedef __attribute__((ext_vector_type(4))) float f32x4;

#define TSTEPS 23
#define ROWS 128

// ws byte offsets
#define WSB_Z  0        // [64][64] f32 sigmoid LUT (16384 B)
#define WSB_B1 16384    // [64 n][168 k] f16 combined table *256 (21504 B)
#define WSB_W2 37888    // [64 n][72 k] f16 rw2 transposed (9216 B)

// ---- precompute: verbatim R4 pre_all (proven, bitwise-stable) ----
__global__ __launch_bounds__(256) void pre_all(
    const float* __restrict__ embed, const float* __restrict__ gw1,
    const float* __restrict__ gb1, const float* __restrict__ gw2,
    const float* __restrict__ gb2, const float* __restrict__ rw1,
    const float* __restrict__ rb1, const float* __restrict__ rw2,
    char* __restrict__ wsc)
{
    __shared__ float sEmb[66 * 64];
    __shared__ float sW[128 * 64];
    __shared__ float sV[64 * 33];
    __shared__ float sU[4 * 32];
    __shared__ float sG[65];
    __shared__ float sRb1[64];

    const int tid = threadIdx.x;
    const int blk = blockIdx.x;

    if (blk < 16) {
        {
            const float4* es = (const float4*)embed;
            float4* ed = (float4*)sEmb;
            for (int i = tid; i < 1024; i += 256) ed[i] = es[i];
            const float4* gs = (const float4*)gw1;
            float4* gd = (float4*)sW;
            for (int i = tid; i < 1024; i += 256) gd[i] = gs[i];
            if (tid < 32) { sG[tid] = gb1[tid]; sG[32 + tid] = gw2[tid]; }
            if (tid == 64) sG[64] = gb2[0];
        }
        __syncthreads();
        #pragma unroll
        for (int i = 0; i < 8; ++i) {
            const int e = tid + i * 256;
            const int s = e >> 5, j = e & 31;
            float acc = 0.f;
            const float* er = sEmb + s * 64;
            #pragma unroll
            for (int k = 0; k < 64; ++k)
                acc = fmaf(er[k], sW[(64 + k) * 32 + j], acc);
            sV[s * 33 + j] = acc;
        }
        if (tid < 128) {
            const int cc = tid >> 5, j = tid & 31;
            const int c = blk * 4 + cc;
            float acc = 0.f;
            const float* er = sEmb + c * 64;
            #pragma unroll
            for (int k = 0; k < 64; ++k)
                acc = fmaf(er[k], sW[k * 32 + j], acc);
            sU[cc * 32 + j] = acc;
        }
        __syncthreads();
        {
            const int cc = tid >> 6, s = tid & 63;
            const int c = blk * 4 + cc;
            double z = (double)sG[64];
            #pragma unroll
            for (int j = 0; j < 32; ++j) {
                const double a = (double)sU[cc * 32 + j] + (double)sV[s * 33 + j] + (double)sG[j];
                if (a > 0.0) z += a * (double)sG[32 + j];
            }
            ((float*)(wsc + WSB_Z))[c * 64 + s] = (float)(1.0 / (1.0 + exp(-z)));
        }
    } else if (blk < 49) {
        {
            const float4* es = (const float4*)embed;
            float4* ed = (float4*)sEmb;
            for (int i = tid; i < 1056; i += 256) ed[i] = es[i];
            const float4* rs = (const float4*)rw1;
            float4* rd = (float4*)sW;
            for (int i = tid; i < 2048; i += 256) rd[i] = rs[i];
            if (tid < 64) sRb1[tid] = rb1[tid];
        }
        __syncthreads();
        const int e = (blk - 16) * 256 + tid;
        if (e < 8320) {
            const int n = e & 63, k = e >> 6;
            float acc;
            if (k < 64) {
                acc = 0.f;
                const float* er = sEmb + k * 64;
                #pragma unroll
                for (int m = 0; m < 64; ++m)
                    acc = fmaf(er[m], sW[(64 + m) * 64 + n], acc);
                acc *= 0.125f * 256.f;
            } else {
                const int t = k - 64;
                acc = sRb1[n];
                const float* er = sEmb + t * 64;
                #pragma unroll
                for (int m = 0; m < 64; ++m)
                    acc = fmaf(er[m], sW[m * 64 + n], acc);
                acc *= 256.f;
            }
            ((_Float16*)(wsc + WSB_B1))[n * 168 + k] = (_Float16)acc;
        }
    } else {
        _Float16* w2t = (_Float16*)(wsc + WSB_W2);
        for (int e = tid; e < 4096; e += 256) {
            const int n = e & 63, j = e >> 6;
            w2t[n * 72 + j] = (_Float16)rw2[j * 64 + n];
        }
        _Float16* b1 = (_Float16*)(wsc + WSB_B1);
        for (int e = tid; e < 2432; e += 256) {
            const int n = e / 38, k = 130 + (e - n * 38);
            b1[n * 168 + k] = (_Float16)0.f;
        }
    }
}

// ---- A-window builders: reconstruct 8-wide f16 A fragment in registers ----
__device__ __forceinline__ f16x8 build_slot_win(const unsigned* s, const unsigned* hb, int ko)
{
    unsigned w0 = 0, w1 = 0, w2 = 0, w3 = 0;
    #pragma unroll
    for (int i = 0; i < 8; ++i) {
        const unsigned d = s[i] - (unsigned)ko;          // wraps huge if below ko
        const unsigned val = (d < 8u) ? (hb[i] << ((d & 1u) * 16)) : 0u;
        const unsigned q = d >> 1;
        w0 |= (q == 0u) ? val : 0u;
        w1 |= (q == 1u) ? val : 0u;
        w2 |= (q == 2u) ? val : 0u;
        w3 |= (q == 3u) ? val : 0u;
    }
    union { unsigned u[4]; f16x8 v; } r;
    r.u[0] = w0; r.u[1] = w1; r.u[2] = w2; r.u[3] = w3;
    return r.v;
}

__device__ __forceinline__ f16x8 build_q_win(int kq, int ko)
{
    const unsigned d = (unsigned)(kq - ko);
    const unsigned val = (d < 8u) ? (0x3C00u << ((d & 1u) * 16)) : 0u;
    const unsigned q = d >> 1;
    union { unsigned u[4]; f16x8 v; } r;
    r.u[0] = (q == 0u) ? val : 0u;
    r.u[1] = (q == 1u) ? val : 0u;
    r.u[2] = (q == 2u) ? val : 0u;
    r.u[3] = (q == 3u) ? val : 0u;
    return r.v;
}

// LDS byte offsets (67840 B arena) — sOut f32[128][68] overlays [0, 34816)
#define L_Z    0        // f32[64][64]   16384
#define L_B1   16384    // f16[64][168]  21504
#define L_W2   37888    // f16[64][72]    9216
#define L_H    47104    // f16[128][72]  18432
#define L_ROW  65536    // uint4[128]     2048
#define L_RB2  67584    // f32[64]         256

__global__ __launch_bounds__(512, 4) void sm_main(
    const int* __restrict__ seqs, const int* __restrict__ qtok,
    const float* __restrict__ rb2, const char* __restrict__ wsc,
    float* __restrict__ out)
{
    __shared__ __align__(16) char smem[67840];
    float*    sZ   = (float*)(smem + L_Z);
    _Float16* sB1  = (_Float16*)(smem + L_B1);
    _Float16* sW2  = (_Float16*)(smem + L_W2);
    _Float16* sH   = (_Float16*)(smem + L_H);
    uint4*    sRow = (uint4*)(smem + L_ROW);
    float*    sRb2 = (float*)(smem + L_RB2);

    const int tid = threadIdx.x;
    const int base = blockIdx.x * ROWS;

    // ---- early token prefetch ----
    unsigned pk[6];
    int qt = 0;
    if (tid < ROWS) {
        const int4* sq = (const int4*)(seqs + (size_t)(base + tid) * 24);
        #pragma unroll
        for (int i = 0; i < 6; ++i) {
            const int4 w4 = sq[i];
            pk[i] = (unsigned)w4.x | ((unsigned)w4.y << 8) |
                    ((unsigned)w4.z << 16) | ((unsigned)w4.w << 24);
        }
        qt = qtok[base + tid];
    }

    // ---- phase 0: stage Z + B1 + W2 + rb2 ----
    {
        const float4* zsrc = (const float4*)(wsc + WSB_Z);
        float4* zdst = (float4*)sZ;
        for (int i = tid; i < 1024; i += 512) zdst[i] = zsrc[i];
        const float4* b1s = (const float4*)(wsc + WSB_B1);
        float4* b1d = (float4*)sB1;
        for (int i = tid; i < 1344; i += 512) b1d[i] = b1s[i];
        const float4* w2s = (const float4*)(wsc + WSB_W2);
        float4* w2d = (float4*)sW2;
        for (int i = tid; i < 576; i += 512) w2d[i] = w2s[i];
        if (tid < 64) sRb2[tid] = rb2[tid];
    }
    __syncthreads();

    // ---- phase 1: scan + publish row info (tid<128) ----
    if (tid < ROWS) {
        unsigned lo = pk[0], hi = pk[1];
        #pragma unroll
        for (int t = 8; t < TSTEPS; ++t) {
            const int c = (int)((pk[t >> 2] >> ((t & 3) * 8)) & 255u);
            const float* zr = sZ + c * 64;
            float b = zr[lo & 63]; int am = 0; float z;
            z = zr[(lo >> 8) & 63];  if (z > b) { b = z; am = 1; }
            z = zr[(lo >> 16) & 63]; if (z > b) { b = z; am = 2; }
            z = zr[lo >> 24];        if (z > b) { b = z; am = 3; }
            z = zr[hi & 63];         if (z > b) { b = z; am = 4; }
            z = zr[(hi >> 8) & 63];  if (z > b) { b = z; am = 5; }
            z = zr[(hi >> 16) & 63]; if (z > b) { b = z; am = 6; }
            z = zr[hi >> 24];        if (z > b) { b = z; am = 7; }
            const unsigned cb = (unsigned)c;
            if (am < 4) { const int sh = am * 8; lo = (lo & ~(255u << sh)) | (cb << sh); }
            else        { const int sh = am * 8 - 32; hi = (hi & ~(255u << sh)) | (cb << sh); }
        }
        int t_[8] = { (int)(lo & 63), (int)((lo >> 8) & 63), (int)((lo >> 16) & 63), (int)(lo >> 24),
                      (int)(hi & 63), (int)((hi >> 8) & 63), (int)((hi >> 16) & 63), (int)(hi >> 24) };
        int tot[8] = {1, 1, 1, 1, 1, 1, 1, 1};
        #pragma unroll
        for (int i = 0; i < 8; ++i)
            #pragma unroll
            for (int j = i + 1; j < 8; ++j) {
                const int eq = (t_[i] == t_[j]);
                tot[i] += eq; tot[j] += eq;
            }
        unsigned tp = 0;
        #pragma unroll
        for (int i = 0; i < 8; ++i) tp |= (unsigned)tot[i] << (4 * i);
        sRow[tid] = make_uint4(lo & 0x3F3F3F3Fu, hi & 0x3F3F3F3Fu, tp, (unsigned)qt);
    }
    __syncthreads();

    // ---- phase 2: MFMA-1  h = A @ B1 (K=160), A built in registers ----
    const int lane = tid & 63;
    const int w = tid >> 6;                 // 0..7
    const int c16 = lane & 15, g = lane >> 4;
    const int arow = w * 16 + c16;          // 0..127

    unsigned sl[8], hb[8];
    int kq;
    {
        const uint4 ri = sRow[arow];
        sl[0] = ri.x & 63u; sl[1] = (ri.x >> 8) & 63u;
        sl[2] = (ri.x >> 16) & 63u; sl[3] = ri.x >> 24;
        sl[4] = ri.y & 63u; sl[5] = (ri.y >> 8) & 63u;
        sl[6] = (ri.y >> 16) & 63u; sl[7] = ri.y >> 24;
        #pragma unroll
        for (int i = 0; i < 8; ++i) {
            const unsigned tot = (ri.z >> (4 * i)) & 15u;
            union { _Float16 h; unsigned short b; } cv;
            cv.h = (_Float16)(float)tot;
            hb[i] = (unsigned)cv.b;
        }
        kq = 64 + (int)ri.w;
    }

    f32x4 a0 = {0.f, 0.f, 0.f, 0.f}, a1 = a0, a2 = a0, a3 = a0;
    #pragma unroll
    for (int ks = 0; ks < 5; ++ks) {
        const int ko = ks * 32 + g * 8;
        const f16x8 af = (ks < 2) ? build_slot_win(sl, hb, ko) : build_q_win(kq, ko);
        const f16x8 b0 = *(const f16x8*)&sB1[(c16) * 168 + ko];
        const f16x8 b1 = *(const f16x8*)&sB1[(16 + c16) * 168 + ko];
        const f16x8 b2 = *(const f16x8*)&sB1[(32 + c16) * 168 + ko];
        const f16x8 b3 = *(const f16x8*)&sB1[(48 + c16) * 168 + ko];
        a0 = __builtin_amdgcn_mfma_f32_16x16x32_f16(af, b0, a0, 0, 0, 0);
        a1 = __builtin_amdgcn_mfma_f32_16x16x32_f16(af, b1, a1, 0, 0, 0);
        a2 = __builtin_amdgcn_mfma_f32_16x16x32_f16(af, b2, a2, 0, 0, 0);
        a3 = __builtin_amdgcn_mfma_f32_16x16x32_f16(af, b3, a3, 0, 0, 0);
    }
    {
        const int rbase = w * 16 + g * 4;
        #pragma unroll
        for (int j = 0; j < 4; ++j) {
            _Float16* hr = sH + (rbase + j) * 72;
            const float v0 = a0[j], v1 = a1[j], v2 = a2[j], v3 = a3[j];
            hr[c16]      = (_Float16)(v0 > 0.f ? v0 : 0.f);
            hr[16 + c16] = (_Float16)(v1 > 0.f ? v1 : 0.f);
            hr[32 + c16] = (_Float16)(v2 > 0.f ? v2 : 0.f);
            hr[48 + c16] = (_Float16)(v3 > 0.f ? v3 : 0.f);
        }
    }
    __syncthreads();

    // ---- phase 3: MFMA-2  logits = relu(h) @ W2t (K=64) ----
    f32x4 d0 = {0.f, 0.f, 0.f, 0.f}, d1 = d0, d2 = d0, d3 = d0;
    #pragma unroll
    for (int ks = 0; ks < 2; ++ks) {
        const int ko = ks * 32 + g * 8;
        const f16x8 af = *(const f16x8*)&sH[arow * 72 + ko];
        const f16x8 b0 = *(const f16x8*)&sW2[(c16) * 72 + ko];
        const f16x8 b1 = *(const f16x8*)&sW2[(16 + c16) * 72 + ko];
        const f16x8 b2 = *(const f16x8*)&sW2[(32 + c16) * 72 + ko];
        const f16x8 b3 = *(const f16x8*)&sW2[(48 + c16) * 72 + ko];
        d0 = __builtin_amdgcn_mfma_f32_16x16x32_f16(af, b0, d0, 0, 0, 0);
        d1 = __builtin_amdgcn_mfma_f32_16x16x32_f16(af, b1, d1, 0, 0, 0);
        d2 = __builtin_amdgcn_mfma_f32_16x16x32_f16(af, b2, d2, 0, 0, 0);
        d3 = __builtin_amdgcn_mfma_f32_16x16x32_f16(af, b3, d3, 0, 0, 0);
    }
    // sZ and sB1 are dead now: overlay output staging f32[128][68] at smem+0
    float* sOut = (float*)(void*)smem;
    {
        const int rbase = w * 16 + g * 4;
        #pragma unroll
        for (int j = 0; j < 4; ++j) {
            float* orow = sOut + (rbase + j) * 68;
            orow[c16]      = d0[j] * (1.f / 256.f) + sRb2[c16];
            orow[16 + c16] = d1[j] * (1.f / 256.f) + sRb2[16 + c16];
            orow[32 + c16] = d2[j] * (1.f / 256.f) + sRb2[32 + c16];
            orow[48 + c16] = d3[j] * (1.f / 256.f) + sRb2[48 + c16];
        }
    }
    __syncthreads();

    // ---- phase 4: coalesced store ----
    #pragma unroll
    for (int r2 = 0; r2 < 4; ++r2) {
        const int idx = r2 * 512 + tid;
        const int row = idx >> 4, c4 = idx & 15;
        *(float4*)(out + (size_t)(base + row) * 64 + c4 * 4) =
            *(const float4*)&sOut[row * 68 + c4 * 4];
    }
}

extern "C" void kernel_launch(void* const* d_in, const int* in_sizes, int n_in,
                              void* d_out, int out_size, void* d_ws, size_t ws_size,
                              hipStream_t stream)
{
    const int* seqs    = (const int*)d_in[0];
    const int* qtok    = (const int*)d_in[1];
    const float* embed = (const float*)d_in[2];
    const float* gw1   = (const float*)d_in[3];
    const float* gb1   = (const float*)d_in[4];
    const float* gw2   = (const float*)d_in[5];
    const float* gb2   = (const float*)d_in[6];
    const float* rw1   = (const float*)d_in[7];
    const float* rb1   = (const float*)d_in[8];
    const float* rw2   = (const float*)d_in[9];
    const float* rb2   = (const float*)d_in[10];
    char* wsc  = (char*)d_ws;
    float* out = (float*)d_out;
    const int B = in_sizes[1];

    pre_all<<<50, 256, 0, stream>>>(embed, gw1, gb1, gw2, gb2, rw1, rb1, rw2, wsc);
    sm_main<<<B / ROWS, 512, 0, stream>>>(seqs, qtok, rb2, wsc, out);
}

// Round 8
// 21.437 us; speedup vs baseline: 3.6719x; 1.1063x over previous
//
#include <hip/hip_runtime.h>
#include <math.h>

typedef __attribute__((ext_vector_type(8))) _Float16 f16x8;
typedef __attribute__((ext_vector_type(4))) float f32x4;

#define TSTEPS 23
#define ROWS 128

// ws byte offsets
#define WSB_Z  0        // [64][64] f32 sigmoid LUT (16384 B)
#define WSB_B1 16384    // [64 n][168 k] f16 combined table *256 (21504 B)
#define WSB_W2 37888    // [64 n][72 k] f16 rw2 transposed (9216 B)

// ---- precompute: same outputs as R4 pre_all, register-cached inner loops ----
__global__ __launch_bounds__(256) void pre_all(
    const float* __restrict__ embed, const float* __restrict__ gw1,
    const float* __restrict__ gb1, const float* __restrict__ gw2,
    const float* __restrict__ gb2, const float* __restrict__ rw1,
    const float* __restrict__ rb1, const float* __restrict__ rw2,
    char* __restrict__ wsc)
{
    __shared__ float sEmb[66 * 64];
    __shared__ float sW[128 * 64];
    __shared__ float sV[64 * 33];
    __shared__ float sU[4 * 32];
    __shared__ float sG[65];
    __shared__ float sRb1[64];

    const int tid = threadIdx.x;
    const int blk = blockIdx.x;

    if (blk < 16) {
        // ---- Z rows c in [blk*4, blk*4+4) ----
        {
            const float4* es = (const float4*)embed;
            float4* ed = (float4*)sEmb;
            for (int i = tid; i < 1024; i += 256) ed[i] = es[i];
            const float4* gs = (const float4*)gw1;
            float4* gd = (float4*)sW;
            for (int i = tid; i < 1024; i += 256) gd[i] = gs[i];
            if (tid < 32) { sG[tid] = gb1[tid]; sG[32 + tid] = gw2[tid]; }
            if (tid == 64) sG[64] = gb2[0];
        }
        __syncthreads();
        // v: thread -> s = tid>>2 (er reg-cached), 8 consecutive j
        {
            const int s = tid >> 2, j0 = (tid & 3) * 8;
            float4 er[16];
            const float4* erp = (const float4*)(sEmb + s * 64);
            #pragma unroll
            for (int q = 0; q < 16; ++q) er[q] = erp[q];
            float acc[8] = {0.f, 0.f, 0.f, 0.f, 0.f, 0.f, 0.f, 0.f};
            #pragma unroll
            for (int k = 0; k < 64; ++k) {
                const float ek = ((const float*)er)[k];      // static idx (unrolled)
                const float4 w0 = *(const float4*)&sW[(64 + k) * 32 + j0];
                const float4 w1 = *(const float4*)&sW[(64 + k) * 32 + j0 + 4];
                acc[0] = fmaf(ek, w0.x, acc[0]); acc[1] = fmaf(ek, w0.y, acc[1]);
                acc[2] = fmaf(ek, w0.z, acc[2]); acc[3] = fmaf(ek, w0.w, acc[3]);
                acc[4] = fmaf(ek, w1.x, acc[4]); acc[5] = fmaf(ek, w1.y, acc[5]);
                acc[6] = fmaf(ek, w1.z, acc[6]); acc[7] = fmaf(ek, w1.w, acc[7]);
            }
            #pragma unroll
            for (int jj = 0; jj < 8; ++jj) sV[s * 33 + j0 + jj] = acc[jj];
        }
        if (tid < 128) {                                 // u: 4 c-rows × 32 j
            const int cc = tid >> 5, j = tid & 31;
            const int c = blk * 4 + cc;
            float acc = 0.f;
            const float* er = sEmb + c * 64;
            #pragma unroll
            for (int k = 0; k < 64; ++k)
                acc = fmaf(er[k], sW[k * 32 + j], acc);
            sU[cc * 32 + j] = acc;
        }
        __syncthreads();
        {
            const int cc = tid >> 6, s = tid & 63;       // DP finisher
            const int c = blk * 4 + cc;
            double z = (double)sG[64];
            #pragma unroll
            for (int j = 0; j < 32; ++j) {
                const double a = (double)sU[cc * 32 + j] + (double)sV[s * 33 + j] + (double)sG[j];
                if (a > 0.0) z += a * (double)sG[32 + j];
            }
            ((float*)(wsc + WSB_Z))[c * 64 + s] = (float)(1.0 / (1.0 + exp(-z)));
        }
    } else if (blk < 49) {
        // ---- B1 combined table: 8320 outputs, 1/thread, er reg-cached ----
        {
            const float4* es = (const float4*)embed;
            float4* ed = (float4*)sEmb;
            for (int i = tid; i < 1056; i += 256) ed[i] = es[i];
            const float4* rs = (const float4*)rw1;
            float4* rd = (float4*)sW;
            for (int i = tid; i < 2048; i += 256) rd[i] = rs[i];
            if (tid < 64) sRb1[tid] = rb1[tid];
        }
        __syncthreads();
        const int e = (blk - 16) * 256 + tid;
        if (e < 8320) {
            const int n = e & 63, k = e >> 6;            // k < 130
            const int trow = (k < 64) ? k : (k - 64);
            const int ofs = (k < 64) ? 64 : 0;
            float4 er[16];
            const float4* erp = (const float4*)(sEmb + trow * 64);
            #pragma unroll
            for (int q = 0; q < 16; ++q) er[q] = erp[q];
            float acc = (k < 64) ? 0.f : sRb1[n];
            #pragma unroll
            for (int m = 0; m < 64; ++m)
                acc = fmaf(((const float*)er)[m], sW[(ofs + m) * 64 + n], acc);
            acc *= (k < 64) ? (0.125f * 256.f) : 256.f;
            ((_Float16*)(wsc + WSB_B1))[n * 168 + k] = (_Float16)acc;
        }
    } else {
        _Float16* w2t = (_Float16*)(wsc + WSB_W2);
        for (int e = tid; e < 4096; e += 256) {
            const int n = e & 63, j = e >> 6;
            w2t[n * 72 + j] = (_Float16)rw2[j * 64 + n];
        }
        _Float16* b1 = (_Float16*)(wsc + WSB_B1);
        for (int e = tid; e < 2432; e += 256) {
            const int n = e / 38, k = 130 + (e - n * 38);
            b1[n * 168 + k] = (_Float16)0.f;
        }
    }
}

// ---- A-window builders (unchanged from R7) ----
__device__ __forceinline__ f16x8 build_slot_win(const unsigned* s, const unsigned* hb, int ko)
{
    unsigned w0 = 0, w1 = 0, w2 = 0, w3 = 0;
    #pragma unroll
    for (int i = 0; i < 8; ++i) {
        const unsigned d = s[i] - (unsigned)ko;
        const unsigned val = (d < 8u) ? (hb[i] << ((d & 1u) * 16)) : 0u;
        const unsigned q = d >> 1;
        w0 |= (q == 0u) ? val : 0u;
        w1 |= (q == 1u) ? val : 0u;
        w2 |= (q == 2u) ? val : 0u;
        w3 |= (q == 3u) ? val : 0u;
    }
    union { unsigned u[4]; f16x8 v; } r;
    r.u[0] = w0; r.u[1] = w1; r.u[2] = w2; r.u[3] = w3;
    return r.v;
}

__device__ __forceinline__ f16x8 build_q_win(int kq, int ko)
{
    const unsigned d = (unsigned)(kq - ko);
    const unsigned val = (d < 8u) ? (0x3C00u << ((d & 1u) * 16)) : 0u;
    const unsigned q = d >> 1;
    union { unsigned u[4]; f16x8 v; } r;
    r.u[0] = (q == 0u) ? val : 0u;
    r.u[1] = (q == 1u) ? val : 0u;
    r.u[2] = (q == 2u) ? val : 0u;
    r.u[3] = (q == 3u) ? val : 0u;
    return r.v;
}

// LDS byte offsets (67840 B arena) — sOut f32[128][68] overlays [0, 34816)
#define L_Z    0
#define L_B1   16384
#define L_W2   37888
#define L_H    47104
#define L_ROW  65536
#define L_RB2  67584

__global__ __launch_bounds__(512, 4) void sm_main(
    const int* __restrict__ seqs, const int* __restrict__ qtok,
    const float* __restrict__ rb2, const char* __restrict__ wsc,
    float* __restrict__ out)
{
    __shared__ __align__(16) char smem[67840];
    float*    sZ   = (float*)(smem + L_Z);
    _Float16* sB1  = (_Float16*)(smem + L_B1);
    _Float16* sW2  = (_Float16*)(smem + L_W2);
    _Float16* sH   = (_Float16*)(smem + L_H);
    uint4*    sRow = (uint4*)(smem + L_ROW);
    float*    sRb2 = (float*)(smem + L_RB2);

    const int tid = threadIdx.x;
    const int base = blockIdx.x * ROWS;

    unsigned pk[6];
    int qt = 0;
    if (tid < ROWS) {
        const int4* sq = (const int4*)(seqs + (size_t)(base + tid) * 24);
        #pragma unroll
        for (int i = 0; i < 6; ++i) {
            const int4 w4 = sq[i];
            pk[i] = (unsigned)w4.x | ((unsigned)w4.y << 8) |
                    ((unsigned)w4.z << 16) | ((unsigned)w4.w << 24);
        }
        qt = qtok[base + tid];
    }

    {
        const float4* zsrc = (const float4*)(wsc + WSB_Z);
        float4* zdst = (float4*)sZ;
        for (int i = tid; i < 1024; i += 512) zdst[i] = zsrc[i];
        const float4* b1s = (const float4*)(wsc + WSB_B1);
        float4* b1d = (float4*)sB1;
        for (int i = tid; i < 1344; i += 512) b1d[i] = b1s[i];
        const float4* w2s = (const float4*)(wsc + WSB_W2);
        float4* w2d = (float4*)sW2;
        for (int i = tid; i < 576; i += 512) w2d[i] = w2s[i];
        if (tid < 64) sRb2[tid] = rb2[tid];
    }
    __syncthreads();

    if (tid < ROWS) {
        unsigned lo = pk[0], hi = pk[1];
        #pragma unroll
        for (int t = 8; t < TSTEPS; ++t) {
            const int c = (int)((pk[t >> 2] >> ((t & 3) * 8)) & 255u);
            const float* zr = sZ + c * 64;
            float b = zr[lo & 63]; int am = 0; float z;
            z = zr[(lo >> 8) & 63];  if (z > b) { b = z; am = 1; }
            z = zr[(lo >> 16) & 63]; if (z > b) { b = z; am = 2; }
            z = zr[lo >> 24];        if (z > b) { b = z; am = 3; }
            z = zr[hi & 63];         if (z > b) { b = z; am = 4; }
            z = zr[(hi >> 8) & 63];  if (z > b) { b = z; am = 5; }
            z = zr[(hi >> 16) & 63]; if (z > b) { b = z; am = 6; }
            z = zr[hi >> 24];        if (z > b) { b = z; am = 7; }
            const unsigned cb = (unsigned)c;
            if (am < 4) { const int sh = am * 8; lo = (lo & ~(255u << sh)) | (cb << sh); }
            else        { const int sh = am * 8 - 32; hi = (hi & ~(255u << sh)) | (cb << sh); }
        }
        int t_[8] = { (int)(lo & 63), (int)((lo >> 8) & 63), (int)((lo >> 16) & 63), (int)(lo >> 24),
                      (int)(hi & 63), (int)((hi >> 8) & 63), (int)((hi >> 16) & 63), (int)(hi >> 24) };
        int tot[8] = {1, 1, 1, 1, 1, 1, 1, 1};
        #pragma unroll
        for (int i = 0; i < 8; ++i)
            #pragma unroll
            for (int j = i + 1; j < 8; ++j) {
                const int eq = (t_[i] == t_[j]);
                tot[i] += eq; tot[j] += eq;
            }
        unsigned tp = 0;
        #pragma unroll
        for (int i = 0; i < 8; ++i) tp |= (unsigned)tot[i] << (4 * i);
        sRow[tid] = make_uint4(lo & 0x3F3F3F3Fu, hi & 0x3F3F3F3Fu, tp, (unsigned)qt);
    }
    __syncthreads();

    const int lane = tid & 63;
    const int w = tid >> 6;
    const int c16 = lane & 15, g = lane >> 4;
    const int arow = w * 16 + c16;

    unsigned sl[8], hb[8];
    int kq;
    {
        const uint4 ri = sRow[arow];
        sl[0] = ri.x & 63u; sl[1] = (ri.x >> 8) & 63u;
        sl[2] = (ri.x >> 16) & 63u; sl[3] = ri.x >> 24;
        sl[4] = ri.y & 63u; sl[5] = (ri.y >> 8) & 63u;
        sl[6] = (ri.y >> 16) & 63u; sl[7] = ri.y >> 24;
        #pragma unroll
        for (int i = 0; i < 8; ++i) {
            const unsigned tot = (ri.z >> (4 * i)) & 15u;
            union { _Float16 h; unsigned short b; } cv;
            cv.h = (_Float16)(float)tot;
            hb[i] = (unsigned)cv.b;
        }
        kq = 64 + (int)ri.w;
    }

    f32x4 a0 = {0.f, 0.f, 0.f, 0.f}, a1 = a0, a2 = a0, a3 = a0;
    #pragma unroll
    for (int ks = 0; ks < 5; ++ks) {
        const int ko = ks * 32 + g * 8;
        const f16x8 af = (ks < 2) ? build_slot_win(sl, hb, ko) : build_q_win(kq, ko);
        const f16x8 b0 = *(const f16x8*)&sB1[(c16) * 168 + ko];
        const f16x8 b1 = *(const f16x8*)&sB1[(16 + c16) * 168 + ko];
        const f16x8 b2 = *(const f16x8*)&sB1[(32 + c16) * 168 + ko];
        const f16x8 b3 = *(const f16x8*)&sB1[(48 + c16) * 168 + ko];
        a0 = __builtin_amdgcn_mfma_f32_16x16x32_f16(af, b0, a0, 0, 0, 0);
        a1 = __builtin_amdgcn_mfma_f32_16x16x32_f16(af, b1, a1, 0, 0, 0);
        a2 = __builtin_amdgcn_mfma_f32_16x16x32_f16(af, b2, a2, 0, 0, 0);
        a3 = __builtin_amdgcn_mfma_f32_16x16x32_f16(af, b3, a3, 0, 0, 0);
    }
    {
        const int rbase = w * 16 + g * 4;
        #pragma unroll
        for (int j = 0; j < 4; ++j) {
            _Float16* hr = sH + (rbase + j) * 72;
            const float v0 = a0[j], v1 = a1[j], v2 = a2[j], v3 = a3[j];
            hr[c16]      = (_Float16)(v0 > 0.f ? v0 : 0.f);
            hr[16 + c16] = (_Float16)(v1 > 0.f ? v1 : 0.f);
            hr[32 + c16] = (_Float16)(v2 > 0.f ? v2 : 0.f);
            hr[48 + c16] = (_Float16)(v3 > 0.f ? v3 : 0.f);
        }
    }
    __syncthreads();

    f32x4 d0 = {0.f, 0.f, 0.f, 0.f}, d1 = d0, d2 = d0, d3 = d0;
    #pragma unroll
    for (int ks = 0; ks < 2; ++ks) {
        const int ko = ks * 32 + g * 8;
        const f16x8 af = *(const f16x8*)&sH[arow * 72 + ko];
        const f16x8 b0 = *(const f16x8*)&sW2[(c16) * 72 + ko];
        const f16x8 b1 = *(const f16x8*)&sW2[(16 + c16) * 72 + ko];
        const f16x8 b2 = *(const f16x8*)&sW2[(32 + c16) * 72 + ko];
        const f16x8 b3 = *(const f16x8*)&sW2[(48 + c16) * 72 + ko];
        d0 = __builtin_amdgcn_mfma_f32_16x16x32_f16(af, b0, d0, 0, 0, 0);
        d1 = __builtin_amdgcn_mfma_f32_16x16x32_f16(af, b1, d1, 0, 0, 0);
        d2 = __builtin_amdgcn_mfma_f32_16x16x32_f16(af, b2, d2, 0, 0, 0);
        d3 = __builtin_amdgcn_mfma_f32_16x16x32_f16(af, b3, d3, 0, 0, 0);
    }
    float* sOut = (float*)(void*)smem;
    {
        const int rbase = w * 16 + g * 4;
        #pragma unroll
        for (int j = 0; j < 4; ++j) {
            float* orow = sOut + (rbase + j) * 68;
            orow[c16]      = d0[j] * (1.f / 256.f) + sRb2[c16];
            orow[16 + c16] = d1[j] * (1.f / 256.f) + sRb2[16 + c16];
            orow[32 + c16] = d2[j] * (1.f / 256.f) + sRb2[32 + c16];
            orow[48 + c16] = d3[j] * (1.f / 256.f) + sRb2[48 + c16];
        }
    }
    __syncthreads();

    #pragma unroll
    for (int r2 = 0; r2 < 4; ++r2) {
        const int idx = r2 * 512 + tid;
        const int row = idx >> 4, c4 = idx & 15;
        *(float4*)(out + (size_t)(base + row) * 64 + c4 * 4) =
            *(const float4*)&sOut[row * 68 + c4 * 4];
    }
}

extern "C" void kernel_launch(void* const* d_in, const int* in_sizes, int n_in,
                              void* d_out, int out_size, void* d_ws, size_t ws_size,
                              hipStream_t stream)
{
    const int* seqs    = (const int*)d_in[0];
    const int* qtok    = (const int*)d_in[1];
    const float* embed = (const float*)d_in[2];
    const float* gw1   = (const float*)d_in[3];
    const float* gb1   = (const float*)d_in[4];
    const float* gw2   = (const float*)d_in[5];
    const float* gb2   = (const float*)d_in[6];
    const float* rw1   = (const float*)d_in[7];
    const float* rb1   = (const float*)d_in[8];
    const float* rw2   = (const float*)d_in[9];
    const float* rb2   = (const float*)d_in[10];
    char* wsc  = (char*)d_ws;
    float* out = (float*)d_out;
    const int B = in_sizes[1];

    pre_all<<<50, 256, 0, stream>>>(embed, gw1, gb1, gw2, gb2, rw1, rb1, rw2, wsc);
    sm_main<<<B / ROWS, 512, 0, stream>>>(seqs, qtok, rb2, wsc, out);
}